// Round 6
// baseline (865.044 us; speedup 1.0000x reference)
//
#include <hip/hip_runtime.h>

#define B_  32
#define L_  2048
#define D_  1024
#define NW_ 409
#define W_  5
#define T_  11
#define H_  8
#define HD_ 128
#define MQ  (B_*NW_)   // 13088
#define MQP 13184      // 103*128 (padded M for q GEMM)

typedef __attribute__((ext_vector_type(16))) float f32x16;
typedef __attribute__((ext_vector_type(8))) __bf16 bf16x8;

__device__ __forceinline__ float b2f(unsigned short u) {
  union { unsigned int i; float f; } x; x.i = ((unsigned int)u) << 16; return x.f;
}
__device__ __forceinline__ unsigned short f2b(float f) {
  union { float f; unsigned int i; } x; x.f = f;
  unsigned int r = (x.i + 0x7FFFu + ((x.i >> 16) & 1u)) >> 16;
  return (unsigned short)r;
}
__device__ __forceinline__ float2 bf2x(unsigned int u) {
  union { unsigned int i; float f; } lo, hi;
  lo.i = u << 16; hi.i = u & 0xffff0000u;
  return make_float2(lo.f, hi.f);
}

__device__ __forceinline__ void async_copy16(const void* g, void* l) {
  __builtin_amdgcn_global_load_lds(
      (const __attribute__((address_space(1))) void*)g,
      (__attribute__((address_space(3))) void*)l, 16, 0, 0);
}

// dot of 8 bf16 pairs packed in uint4
__device__ __forceinline__ float dot8(uint4 a, uint4 b) {
  float2 x, y; float s = 0.f;
  x = bf2x(a.x); y = bf2x(b.x); s += x.x * y.x + x.y * y.y;
  x = bf2x(a.y); y = bf2x(b.y); s += x.x * y.x + x.y * y.y;
  x = bf2x(a.z); y = bf2x(b.z); s += x.x * y.x + x.y * y.y;
  x = bf2x(a.w); y = bf2x(b.w); s += x.x * y.x + x.y * y.y;
  return s;
}
// o += w * (2 bf16 in v)
__device__ __forceinline__ void fma2(float2& o, unsigned int v, float w) {
  float2 f = bf2x(v); o.x += w * f.x; o.y += w * f.y;
}

// ================= mega1: {cvt_x | cvt_w | fill | wc_part} by block range ====
// All four are mutually independent; merging removes 3 launch gaps and makes
// cvt_x's cost directly visible as this dispatch's duration (instrumentation).
__device__ __forceinline__ void cvt_body(const float* __restrict__ in,
                                         unsigned short* __restrict__ out,
                                         int i0, int stride, int n4) {
  for (int i = i0; i < n4; i += stride) {
    float4 v = ((const float4*)in)[i];
    ushort4 o;
    o.x = f2b(v.x); o.y = f2b(v.y); o.z = f2b(v.z); o.w = f2b(v.w);
    ((ushort4*)out)[i] = o;
  }
}
__global__ __launch_bounds__(256)
void mega1_kernel(const float* __restrict__ x, unsigned short* __restrict__ xb,
                  const float* __restrict__ ipw, unsigned short* __restrict__ win,
                  const float* __restrict__ ow, const float* __restrict__ opw,
                  float* __restrict__ Wcp, float* __restrict__ out) {
  const int blk = blockIdx.x, tid = threadIdx.x;
  if (blk < 2048) {                       // cvt_x: 256 MB fp32 -> 128 MB bf16
    cvt_body(x, xb, blk * 256 + tid, 2048 * 256, 16777216);
  } else if (blk < 2304) {                // cvt_w: in_proj_w -> bf16
    cvt_body(ipw, win, (blk - 2048) * 256 + tid, 256 * 256, 786432);
  } else if (blk < 2816) {                // fill out with log(0.5)
    out[(blk - 2304) * 256 + tid] = -0.69314718055994531f;
  } else {                                // wc_part: 128 blocks
    int bb = blk - 2816;
    int eb = bb >> 3, seg = bb & 7;
    int d = seg * 256 + tid;              // 0..2047
    int c = d >> 10, dd = d & 1023;
    float acc = 0.f;
    int e0 = eb * 64;
#pragma unroll 8
    for (int e = e0; e < e0 + 64; e++) acc += ow[c * D_ + e] * opw[e * D_ + dd];
    Wcp[eb * 2048 + d] = acc;
  }
}

__global__ void wc_reduce_kernel(const float* __restrict__ Wcp,
                                 const float* __restrict__ ow, const float* __restrict__ opb,
                                 const float* __restrict__ ob,
                                 float* __restrict__ Wc, float* __restrict__ bc) {
  int d = blockIdx.x * 256 + threadIdx.x;
  float s = 0.f;
#pragma unroll
  for (int eb = 0; eb < 16; eb++) s += Wcp[eb * 2048 + d];
  Wc[d] = s;
  if (blockIdx.x == 0 && threadIdx.x < 128) {
    int c = threadIdx.x >> 6, lane = threadIdx.x & 63;
    float p = 0.f;
#pragma unroll
    for (int j = 0; j < 16; j++) p += ow[c * D_ + lane + 64 * j] * opb[lane + 64 * j];
#pragma unroll
    for (int off = 32; off > 0; off >>= 1) p += __shfl_down(p, off);
    if (lane == 0) bc[c] = p + ob[c];
  }
}

// ---------------- NT GEMM, bf16 A, BK=64, 32x32x16 MFMA (R2 layout) ----------
// C[M,N] = A[M,K] @ Bw[N,K]^T (+bias[N]); 128x128 tile, 4 waves 2x2, wave does
// 2x2 32x32 tiles. LDS slot c holds (r=c>>3, kc=((c&7)-r)&7); read quad
// (c8+rb)&7 cycles with rb. NOTE: this rotated layout carries ~3.4e7
// SQ_LDS_BANK_CONFLICT (~1 extra cyc/ds_read_b128) but those cycles are hidden
// behind the 2-phase stage+barrier critical path (T2 regime-gate, m252) --
// R3's conflict-free chunk-major layout destroyed global coalescing and was
// 1.7x SLOWER. Do not "fix" conflicts without an 8-phase schedule; and per
// m248 (K=1024 grouped GEMM) 8-phase at short K is only ~1.12x -- deferred.
// GATHER: A-row rg maps to x-row b*L + W*n + W (query-center gather fused in);
// pad rows (rg>=MQ) clamp to row 0, their C output is never read.
// XCD swizzle: remap so each XCD owns a contiguous chunk of logical tiles.
template<bool GATHER>
__global__ __launch_bounds__(256)
void gemm_bt_kernel(const unsigned short* __restrict__ A,
                    const unsigned short* __restrict__ Bw,
                    unsigned short* __restrict__ C,
                    const float* __restrict__ bias,
                    int N, int K) {
  __shared__ __align__(16) unsigned short sA[128 * 64];
  __shared__ __align__(16) unsigned short sB[128 * 64];
  const int h = blockIdx.y * gridDim.x + blockIdx.x;
  const int chunk = (gridDim.x * gridDim.y) >> 3;   // grid total % 8 == 0
  const int lg = (h & 7) * chunk + (h >> 3);
  const int bx = lg % gridDim.x, by = lg / gridDim.x;
  const int tid = threadIdx.x;
  const int row0 = by * 128;
  const int col0 = bx * 128;
  const int wave = tid >> 6, lane = tid & 63;
  const int wm = wave & 1, wn = wave >> 1;
  const int l31 = lane & 31, lh = lane >> 5;

  // ---- staging coords (each: 1024 16B chunks) ----
  const unsigned short* Asrc[4];
  const unsigned short* Bsrc[4];
#pragma unroll
  for (int u = 0; u < 4; u++) {
    int c = tid + 256 * u;
    int r = c >> 3, kc = ((c & 7) - r) & 7;
    Bsrc[u] = Bw + (size_t)(col0 + r) * K + kc * 8;
    size_t arow;
    if constexpr (GATHER) {
      int mm = row0 + r;
      if (mm >= MQ) mm = 0;                 // pad rows: any valid src
      int b = mm / NW_, n = mm - b * NW_;
      arow = (size_t)b * L_ + (size_t)(W_ * n + W_);
    } else {
      arow = (size_t)(row0 + r);
    }
    Asrc[u] = A + arow * K + kc * 8;
  }

  // ---- fragment read offsets (in shorts) ----
  int offA[4][2], offB[4][2];
#pragma unroll
  for (int kc = 0; kc < 4; kc++) {
    int c8 = kc * 2 + lh;
#pragma unroll
    for (int i = 0; i < 2; i++) {
      int rb = wn * 64 + i * 32 + l31;
      offB[kc][i] = (rb * 8 + ((c8 + rb) & 7)) * 8;
      int ra = wm * 64 + i * 32 + l31;
      offA[kc][i] = (ra * 8 + ((c8 + ra) & 7)) * 8;
    }
  }

  f32x16 acc[2][2];
#pragma unroll
  for (int i = 0; i < 2; i++)
#pragma unroll
    for (int j = 0; j < 2; j++) acc[i][j] = (f32x16)0.0f;

  for (int kt = 0; kt < K; kt += 64) {
#pragma unroll
    for (int u = 0; u < 4; u++)
      async_copy16(Asrc[u] + kt, &sA[(tid + 256 * u) * 8]);
#pragma unroll
    for (int u = 0; u < 4; u++)
      async_copy16(Bsrc[u] + kt, &sB[(tid + 256 * u) * 8]);
    __syncthreads();
#pragma unroll
    for (int kc = 0; kc < 4; kc++) {
      bf16x8 a0 = *(const bf16x8*)&sA[offA[kc][0]];
      bf16x8 a1 = *(const bf16x8*)&sA[offA[kc][1]];
      bf16x8 b0 = *(const bf16x8*)&sB[offB[kc][0]];
      bf16x8 b1 = *(const bf16x8*)&sB[offB[kc][1]];
      acc[0][0] = __builtin_amdgcn_mfma_f32_32x32x16_bf16(a0, b0, acc[0][0], 0, 0, 0);
      acc[0][1] = __builtin_amdgcn_mfma_f32_32x32x16_bf16(a0, b1, acc[0][1], 0, 0, 0);
      acc[1][0] = __builtin_amdgcn_mfma_f32_32x32x16_bf16(a1, b0, acc[1][0], 0, 0, 0);
      acc[1][1] = __builtin_amdgcn_mfma_f32_32x32x16_bf16(a1, b1, acc[1][1], 0, 0, 0);
    }
    __syncthreads();
  }

  // C/D frag (m74/m101): col=lane&31, row=(reg&3)+8*(reg>>2)+4*(lane>>5)
#pragma unroll
  for (int i = 0; i < 2; i++) {
#pragma unroll
    for (int j = 0; j < 2; j++) {
      int gc = col0 + wn * 64 + j * 32 + l31;
      float bv = bias ? bias[gc] : 0.0f;
#pragma unroll
      for (int r = 0; r < 16; r++) {
        int gr = row0 + wm * 64 + i * 32 + (r & 3) + 8 * (r >> 2) + 4 * lh;
        C[(size_t)gr * N + gc] = f2b(acc[i][j][r] + bv);
      }
    }
  }
}

// ---------------- windowed attention + fused classifier head -----------------
// TWO CONSECUTIVE WINDOWS PER WAVE (R5-proven). Shared K/V loads for the 6/11
// overlapping positions; boundary pairs take a wave-uniform separate path.
// Lane l owns dims [16l,16l+16) -> head l>>3. No LDS, no __syncthreads.
// 4 wave-pairs/block; bijective XCD swizzle over 1636 blocks (4x205 + 4x204).
__global__ __launch_bounds__(256)
void attn_kernel(const unsigned short* __restrict__ q,
                 const unsigned short* __restrict__ kv,
                 const float* __restrict__ Wc, const float* __restrict__ bc,
                 float* __restrict__ out) {
  const int g = blockIdx.x;                     // 0..1635
  const int xcd = g & 7, idx = g >> 3;
  const int logical = (xcd < 4) ? (xcd * 205 + idx)
                                : (820 + (xcd - 4) * 204 + idx);
  const int wave = threadIdx.x >> 6, lane = threadIdx.x & 63;
  const int p = logical * 4 + wave;             // pair id 0..6543
  const int m0 = 2 * p, m1 = m0 + 1;
  const int b0 = m0 / NW_, n0 = m0 - b0 * NW_;
  const int b1 = m1 / NW_, n1 = m1 - b1 * NW_;
  const bool adj = (n0 != NW_ - 1);             // same b, n1 = n0+1
  const size_t rb0 = (size_t)b0 * L_ * 2048;
  const size_t rb1 = (size_t)b1 * L_ * 2048;
  const int d0 = lane * 16;

  const unsigned short* qp0 = q + (size_t)m0 * D_ + d0;
  uint4 qa0 = *(const uint4*)qp0, qa1 = *(const uint4*)(qp0 + 8);
  const unsigned short* qp1 = q + (size_t)m1 * D_ + d0;
  uint4 qb0 = *(const uint4*)qp1, qb1 = *(const uint4*)(qp1 + 8);

  // ---- scores over 16 shared positions ----
  float svA[T_], svB[T_];
#pragma unroll
  for (int t = 0; t < T_ + W_; t++) {
    uint4 k0, k1;
    bool liveA = false;
    if (t < T_) {                               // window A position
      int posA = W_ * n0 + t;
      float sc = 0.f;
      if (posA < L_) {
        const unsigned short* kr = kv + rb0 + (size_t)posA * 2048 + d0;
        k0 = *(const uint4*)kr; k1 = *(const uint4*)(kr + 8);
        liveA = true;
        sc = dot8(qa0, k0) + dot8(qa1, k1);
      }
      sc += __shfl_xor(sc, 1);
      sc += __shfl_xor(sc, 2);
      sc += __shfl_xor(sc, 4);
      svA[t] = sc * 0.08838834764831845f;       // 1/sqrt(128)
    }
    if (t >= W_) {                              // window B position
      int tb = t - W_;
      int posB = W_ * n1 + tb;
      float sc = 0.f;
      if (posB < L_) {
        uint4 j0, j1;
        if (adj && liveA) { j0 = k0; j1 = k1; } // same row as A's load
        else {
          const unsigned short* kr = kv + rb1 + (size_t)posB * 2048 + d0;
          j0 = *(const uint4*)kr; j1 = *(const uint4*)(kr + 8);
        }
        sc = dot8(qb0, j0) + dot8(qb1, j1);
      }
      sc += __shfl_xor(sc, 1);
      sc += __shfl_xor(sc, 2);
      sc += __shfl_xor(sc, 4);
      svB[tb] = sc * 0.08838834764831845f;
    }
  }

  // ---- softmax per window ----
  {
    float mx = svA[0];
#pragma unroll
    for (int t = 1; t < T_; t++) mx = fmaxf(mx, svA[t]);
    float sum = 0.f;
#pragma unroll
    for (int t = 0; t < T_; t++) { svA[t] = expf(svA[t] - mx); sum += svA[t]; }
    float inv = 1.f / sum;
#pragma unroll
    for (int t = 0; t < T_; t++) svA[t] *= inv;
  }
  {
    float mx = svB[0];
#pragma unroll
    for (int t = 1; t < T_; t++) mx = fmaxf(mx, svB[t]);
    float sum = 0.f;
#pragma unroll
    for (int t = 0; t < T_; t++) { svB[t] = expf(svB[t] - mx); sum += svB[t]; }
    float inv = 1.f / sum;
#pragma unroll
    for (int t = 0; t < T_; t++) svB[t] *= inv;
  }

  // ---- PV over the same 16 shared positions ----
  float2 oA[8], oB[8];
#pragma unroll
  for (int j = 0; j < 8; j++) { oA[j] = make_float2(0.f, 0.f); oB[j] = make_float2(0.f, 0.f); }
#pragma unroll
  for (int t = 0; t < T_ + W_; t++) {
    uint4 v0, v1;
    bool liveA = false;
    if (t < T_) {
      int posA = W_ * n0 + t;
      if (posA < L_) {
        const unsigned short* vr = kv + rb0 + (size_t)posA * 2048 + 1024 + d0;
        v0 = *(const uint4*)vr; v1 = *(const uint4*)(vr + 8);
        liveA = true;
        float w = svA[t];
        fma2(oA[0], v0.x, w); fma2(oA[1], v0.y, w);
        fma2(oA[2], v0.z, w); fma2(oA[3], v0.w, w);
        fma2(oA[4], v1.x, w); fma2(oA[5], v1.y, w);
        fma2(oA[6], v1.z, w); fma2(oA[7], v1.w, w);
      }
    }
    if (t >= W_) {
      int tb = t - W_;
      int posB = W_ * n1 + tb;
      if (posB < L_) {
        uint4 u0, u1;
        if (adj && liveA) { u0 = v0; u1 = v1; }
        else {
          const unsigned short* vr = kv + rb1 + (size_t)posB * 2048 + 1024 + d0;
          u0 = *(const uint4*)vr; u1 = *(const uint4*)(vr + 8);
        }
        float w = svB[tb];
        fma2(oB[0], u0.x, w); fma2(oB[1], u0.y, w);
        fma2(oB[2], u0.z, w); fma2(oB[3], u0.w, w);
        fma2(oB[4], u1.x, w); fma2(oB[5], u1.y, w);
        fma2(oB[6], u1.z, w); fma2(oB[7], u1.w, w);
      }
    }
  }

  // ---- fused classifier head for both windows ----
  float pA0 = 0.f, pA1 = 0.f, pB0 = 0.f, pB1 = 0.f;
#pragma unroll
  for (int j = 0; j < 4; j++) {
    float4 w0 = ((const float4*)(Wc + d0))[j];
    float4 w1 = ((const float4*)(Wc + D_ + d0))[j];
    pA0 += oA[2*j].x * w0.x + oA[2*j].y * w0.y + oA[2*j+1].x * w0.z + oA[2*j+1].y * w0.w;
    pA1 += oA[2*j].x * w1.x + oA[2*j].y * w1.y + oA[2*j+1].x * w1.z + oA[2*j+1].y * w1.w;
    pB0 += oB[2*j].x * w0.x + oB[2*j].y * w0.y + oB[2*j+1].x * w0.z + oB[2*j+1].y * w0.w;
    pB1 += oB[2*j].x * w1.x + oB[2*j].y * w1.y + oB[2*j+1].x * w1.z + oB[2*j+1].y * w1.w;
  }
#pragma unroll
  for (int off = 32; off > 0; off >>= 1) {
    pA0 += __shfl_down(pA0, off);
    pA1 += __shfl_down(pA1, off);
    pB0 += __shfl_down(pB0, off);
    pB1 += __shfl_down(pB1, off);
  }

  if (lane == 0) {
    {
      float s0 = pA0 + bc[0], s1 = pA1 + bc[1];
      float smx = fmaxf(s0, s1);
      float lse = smx + logf(expf(s0 - smx) + expf(s1 - smx));
      size_t row = (size_t)b0 * L_ + (size_t)(W_ * n0);
      out[row * 2 + 0] = s0 - lse;
      out[row * 2 + 1] = s1 - lse;
    }
    {
      float s0 = pB0 + bc[0], s1 = pB1 + bc[1];
      float smx = fmaxf(s0, s1);
      float lse = smx + logf(expf(s0 - smx) + expf(s1 - smx));
      size_t row = (size_t)b1 * L_ + (size_t)(W_ * n1);
      out[row * 2 + 0] = s0 - lse;
      out[row * 2 + 1] = s1 - lse;
    }
  }
}

extern "C" void kernel_launch(void* const* d_in, const int* in_sizes, int n_in,
                              void* d_out, int out_size, void* d_ws, size_t ws_size,
                              hipStream_t stream) {
  const float* x          = (const float*)d_in[0];
  const float* in_proj_w  = (const float*)d_in[1];
  const float* in_proj_b  = (const float*)d_in[2];
  const float* out_proj_w = (const float*)d_in[3];
  const float* out_proj_b = (const float*)d_in[4];
  const float* out_w      = (const float*)d_in[5];
  const float* out_b      = (const float*)d_in[6];
  float* out = (float*)d_out;

  // workspace (~432 MB):
  //   [0, 32MB)    qout (MQP x 1024 bf16)
  //   [32MB)       in_proj_w bf16 (wq|wk|wv)  (6.3 MB)
  //   [40MB)       Wc (2x1024 f32), bc, Wcp (16x2048 f32)
  //   [48MB)       xb = x bf16, (B*L) x 1024  (128 MB)
  //   [176MB)      kv = K|V bf16, (B*L) x 2048 (256 MB)
  char* ws = (char*)d_ws;
  unsigned short* qout = (unsigned short*)(ws);
  unsigned short* win  = (unsigned short*)(ws + 33554432);
  float*          Wc   = (float*)(ws + 41943040);
  float*          bc   = (float*)(ws + 41951232);
  float*          Wcp  = (float*)(ws + 41959424);
  unsigned short* xb   = (unsigned short*)(ws + 50331648);
  unsigned short* kvb  = (unsigned short*)(ws + 184549376);

  // mega1: cvt_x [0,2048) | cvt_w [2048,2304) | fill [2304,2816) | wc_part [2816,2944)
  mega1_kernel<<<2944, 256, 0, stream>>>(x, xb, in_proj_w, win,
                                         out_w, out_proj_w, Wcp, out);
  wc_reduce_kernel<<<8, 256, 0, stream>>>(Wcp, out_w, out_proj_b, out_b, Wc, bc);

  // KV GEMM split into two M-halves (instrumentation: each ~182 us; any hidden
  // dispatch in (182,362) us now becomes #1 in top-5). Disjoint A/C; B re-read
  // is only 4 MB. Grid per half: 16 x 256 = 4096 blocks (%8==0 for swizzle).
  dim3 gkvh(16, 256);
  gemm_bt_kernel<false><<<gkvh, 256, 0, stream>>>(xb, win + 1048576, kvb,
                                                  in_proj_b + 1024, 2048, 1024);
  gemm_bt_kernel<false><<<gkvh, 256, 0, stream>>>(xb + (size_t)32768 * 1024,
                                                  win + 1048576,
                                                  kvb + (size_t)32768 * 2048,
                                                  in_proj_b + 1024, 2048, 1024);
  dim3 gq(8, 103);    // M=13184, N=1024; A = bf16 xb with fused center-gather
  gemm_bt_kernel<true><<<gq, 256, 0, stream>>>(xb, win, qout, in_proj_b, 1024, 1024);

  attn_kernel<<<1636, 256, 0, stream>>>(qout, kvb, Wc, bc, out);
}

// Round 7
// 717.168 us; speedup vs baseline: 1.2062x; 1.2062x over previous
//
#include <hip/hip_runtime.h>

#define B_  32
#define L_  2048
#define D_  1024
#define NW_ 409
#define W_  5
#define T_  11
#define H_  8
#define HD_ 128
#define MQ  (B_*NW_)   // 13088
#define MQP 13184      // 103*128 (padded M for q GEMM)

typedef __attribute__((ext_vector_type(16))) float f32x16;
typedef __attribute__((ext_vector_type(4)))  float f32x4;
typedef __attribute__((ext_vector_type(8))) __bf16 bf16x8;

__device__ __forceinline__ float b2f(unsigned short u) {
  union { unsigned int i; float f; } x; x.i = ((unsigned int)u) << 16; return x.f;
}
__device__ __forceinline__ unsigned short f2b(float f) {
  union { float f; unsigned int i; } x; x.f = f;
  unsigned int r = (x.i + 0x7FFFu + ((x.i >> 16) & 1u)) >> 16;
  return (unsigned short)r;
}
__device__ __forceinline__ float2 bf2x(unsigned int u) {
  union { unsigned int i; float f; } lo, hi;
  lo.i = u << 16; hi.i = u & 0xffff0000u;
  return make_float2(lo.f, hi.f);
}

__device__ __forceinline__ void async_copy16(const void* g, void* l) {
  __builtin_amdgcn_global_load_lds(
      (const __attribute__((address_space(1))) void*)g,
      (__attribute__((address_space(3))) void*)l, 16, 0, 0);
}

// dot of 8 bf16 pairs packed in uint4
__device__ __forceinline__ float dot8(uint4 a, uint4 b) {
  float2 x, y; float s = 0.f;
  x = bf2x(a.x); y = bf2x(b.x); s += x.x * y.x + x.y * y.y;
  x = bf2x(a.y); y = bf2x(b.y); s += x.x * y.x + x.y * y.y;
  x = bf2x(a.z); y = bf2x(b.z); s += x.x * y.x + x.y * y.y;
  x = bf2x(a.w); y = bf2x(b.w); s += x.x * y.x + x.y * y.y;
  return s;
}

// ================= mega1: {cvt_x | cvt_w | fill | wc_part} by block range ====
__device__ __forceinline__ void cvt_body(const float* __restrict__ in,
                                         unsigned short* __restrict__ out,
                                         int i0, int stride, int n4) {
  for (int i = i0; i < n4; i += stride) {
    float4 v = ((const float4*)in)[i];
    ushort4 o;
    o.x = f2b(v.x); o.y = f2b(v.y); o.z = f2b(v.z); o.w = f2b(v.w);
    ((ushort4*)out)[i] = o;
  }
}
__global__ __launch_bounds__(256)
void mega1_kernel(const float* __restrict__ x, unsigned short* __restrict__ xb,
                  const float* __restrict__ ipw, unsigned short* __restrict__ win,
                  const float* __restrict__ ow, const float* __restrict__ opw,
                  float* __restrict__ Wcp, float* __restrict__ out) {
  const int blk = blockIdx.x, tid = threadIdx.x;
  if (blk < 2048) {                       // cvt_x: 256 MB fp32 -> 128 MB bf16
    cvt_body(x, xb, blk * 256 + tid, 2048 * 256, 16777216);
  } else if (blk < 2304) {                // cvt_w: in_proj_w -> bf16
    cvt_body(ipw, win, (blk - 2048) * 256 + tid, 256 * 256, 786432);
  } else if (blk < 2816) {                // fill out with log(0.5)
    out[(blk - 2304) * 256 + tid] = -0.69314718055994531f;
  } else {                                // wc_part: 128 blocks
    int bb = blk - 2816;
    int eb = bb >> 3, seg = bb & 7;
    int d = seg * 256 + tid;              // 0..2047
    int c = d >> 10, dd = d & 1023;
    float acc = 0.f;
    int e0 = eb * 64;
#pragma unroll 8
    for (int e = e0; e < e0 + 64; e++) acc += ow[c * D_ + e] * opw[e * D_ + dd];
    Wcp[eb * 2048 + d] = acc;
  }
}

__global__ void wc_reduce_kernel(const float* __restrict__ Wcp,
                                 const float* __restrict__ ow, const float* __restrict__ opb,
                                 const float* __restrict__ ob,
                                 float* __restrict__ Wc, float* __restrict__ bc) {
  int d = blockIdx.x * 256 + threadIdx.x;
  float s = 0.f;
#pragma unroll
  for (int eb = 0; eb < 16; eb++) s += Wcp[eb * 2048 + d];
  Wc[d] = s;
  if (blockIdx.x == 0 && threadIdx.x < 128) {
    int c = threadIdx.x >> 6, lane = threadIdx.x & 63;
    float p = 0.f;
#pragma unroll
    for (int j = 0; j < 16; j++) p += ow[c * D_ + lane + 64 * j] * opb[lane + 64 * j];
#pragma unroll
    for (int off = 32; off > 0; off >>= 1) p += __shfl_down(p, off);
    if (lane == 0) bc[c] = p + ob[c];
  }
}

// ================ WvH: fold Wc into the V projection (V-elimination) =========
// WvH[c,h,e] = sum_{d in head h} Wc[c,d] * wv[d,e]  (2x8x1024, bf16 out).
// v-bias folds to a constant per class (softmax sums to 1): bc[c] += sum gb.
// 16 blocks = (c,h); re-sums Wcp itself (no dep on wc_reduce's Wc), but the
// bc atomicAdd requires wc_reduce to have run first (stream-ordered).
__global__ __launch_bounds__(256)
void wvh_kernel(const float* __restrict__ Wcp, const float* __restrict__ ipw,
                const float* __restrict__ ipb, float* __restrict__ bc,
                unsigned short* __restrict__ WvHb) {
  const int c = blockIdx.x >> 3, h = blockIdx.x & 7;
  const int tid = threadIdx.x;
  __shared__ float wcs[128];
  if (tid < 128) {
    float s = 0.f;
#pragma unroll
    for (int eb = 0; eb < 16; eb++) s += Wcp[eb * 2048 + c * 1024 + h * 128 + tid];
    wcs[tid] = s;
  }
  __syncthreads();
  const float* wv = ipw + 2048 * 1024;
#pragma unroll
  for (int j = 0; j < 4; j++) {
    int e = j * 256 + tid;
    float acc = 0.f;
    for (int dd = 0; dd < 128; dd++)
      acc += wcs[dd] * wv[(size_t)(h * 128 + dd) * 1024 + e];
    WvHb[(c * 8 + h) * 1024 + e] = f2b(acc);
  }
  if (tid == 0) {
    float gb = 0.f;
    for (int dd = 0; dd < 128; dd++) gb += wcs[dd] * ipb[2048 + h * 128 + dd];
    atomicAdd(&bc[c], gb);
  }
}

// ================ G = xb @ WvHb^T : (65536 x 16), fp32 out ===================
// One wave per 16 rows; 16x16x32 MFMA. A frag: row=lane&15, k=(lane>>4)*8+j;
// B frag: col(out)=lane&15, same k. C/D: col=lane&15, row=(lane>>4)*4+reg
// (m89-verified mapping). WvHb rows are o = c*8+h.
__global__ __launch_bounds__(256)
void gk_kernel(const unsigned short* __restrict__ xb,
               const unsigned short* __restrict__ WvHb,
               float* __restrict__ G) {
  const int wave = threadIdx.x >> 6, lane = threadIdx.x & 63;
  const int r0 = (blockIdx.x * 4 + wave) * 16;
  const int l15 = lane & 15, kh = lane >> 4;
  const unsigned short* ap = xb + (size_t)(r0 + l15) * 1024 + kh * 8;
  const unsigned short* bp = WvHb + l15 * 1024 + kh * 8;
  f32x4 acc = (f32x4)0.0f;
  for (int kt = 0; kt < 1024; kt += 32) {
    bf16x8 a = *(const bf16x8*)(ap + kt);
    bf16x8 b = *(const bf16x8*)(bp + kt);
    acc = __builtin_amdgcn_mfma_f32_16x16x32_bf16(a, b, acc, 0, 0, 0);
  }
#pragma unroll
  for (int r = 0; r < 4; r++)
    G[(size_t)(r0 + kh * 4 + r) * 16 + l15] = acc[r];
}

// ---------------- NT GEMM, bf16 A, BK=64, 32x32x16 MFMA (R2 layout) ----------
// Proven kernel, unchanged. Rotated-LDS conflicts (~1.7e7) are hidden behind
// the 2-phase stage+barrier path (T2 regime-gate, m252); R3's "fix" was 1.7x
// slower. Now used for K-only (N=1024) + q (N=1024, GATHER).
template<bool GATHER>
__global__ __launch_bounds__(256)
void gemm_bt_kernel(const unsigned short* __restrict__ A,
                    const unsigned short* __restrict__ Bw,
                    unsigned short* __restrict__ C,
                    const float* __restrict__ bias,
                    int N, int K) {
  __shared__ __align__(16) unsigned short sA[128 * 64];
  __shared__ __align__(16) unsigned short sB[128 * 64];
  const int h = blockIdx.y * gridDim.x + blockIdx.x;
  const int chunk = (gridDim.x * gridDim.y) >> 3;   // grid total % 8 == 0
  const int lg = (h & 7) * chunk + (h >> 3);
  const int bx = lg % gridDim.x, by = lg / gridDim.x;
  const int tid = threadIdx.x;
  const int row0 = by * 128;
  const int col0 = bx * 128;
  const int wave = tid >> 6, lane = tid & 63;
  const int wm = wave & 1, wn = wave >> 1;
  const int l31 = lane & 31, lh = lane >> 5;

  const unsigned short* Asrc[4];
  const unsigned short* Bsrc[4];
#pragma unroll
  for (int u = 0; u < 4; u++) {
    int c = tid + 256 * u;
    int r = c >> 3, kc = ((c & 7) - r) & 7;
    Bsrc[u] = Bw + (size_t)(col0 + r) * K + kc * 8;
    size_t arow;
    if constexpr (GATHER) {
      int mm = row0 + r;
      if (mm >= MQ) mm = 0;                 // pad rows: any valid src
      int b = mm / NW_, n = mm - b * NW_;
      arow = (size_t)b * L_ + (size_t)(W_ * n + W_);
    } else {
      arow = (size_t)(row0 + r);
    }
    Asrc[u] = A + arow * K + kc * 8;
  }

  int offA[4][2], offB[4][2];
#pragma unroll
  for (int kc = 0; kc < 4; kc++) {
    int c8 = kc * 2 + lh;
#pragma unroll
    for (int i = 0; i < 2; i++) {
      int rb = wn * 64 + i * 32 + l31;
      offB[kc][i] = (rb * 8 + ((c8 + rb) & 7)) * 8;
      int ra = wm * 64 + i * 32 + l31;
      offA[kc][i] = (ra * 8 + ((c8 + ra) & 7)) * 8;
    }
  }

  f32x16 acc[2][2];
#pragma unroll
  for (int i = 0; i < 2; i++)
#pragma unroll
    for (int j = 0; j < 2; j++) acc[i][j] = (f32x16)0.0f;

  for (int kt = 0; kt < K; kt += 64) {
#pragma unroll
    for (int u = 0; u < 4; u++)
      async_copy16(Asrc[u] + kt, &sA[(tid + 256 * u) * 8]);
#pragma unroll
    for (int u = 0; u < 4; u++)
      async_copy16(Bsrc[u] + kt, &sB[(tid + 256 * u) * 8]);
    __syncthreads();
#pragma unroll
    for (int kc = 0; kc < 4; kc++) {
      bf16x8 a0 = *(const bf16x8*)&sA[offA[kc][0]];
      bf16x8 a1 = *(const bf16x8*)&sA[offA[kc][1]];
      bf16x8 b0 = *(const bf16x8*)&sB[offB[kc][0]];
      bf16x8 b1 = *(const bf16x8*)&sB[offB[kc][1]];
      acc[0][0] = __builtin_amdgcn_mfma_f32_32x32x16_bf16(a0, b0, acc[0][0], 0, 0, 0);
      acc[0][1] = __builtin_amdgcn_mfma_f32_32x32x16_bf16(a0, b1, acc[0][1], 0, 0, 0);
      acc[1][0] = __builtin_amdgcn_mfma_f32_32x32x16_bf16(a1, b0, acc[1][0], 0, 0, 0);
      acc[1][1] = __builtin_amdgcn_mfma_f32_32x32x16_bf16(a1, b1, acc[1][1], 0, 0, 0);
    }
    __syncthreads();
  }

  // C/D frag (m74/m101): col=lane&31, row=(reg&3)+8*(reg>>2)+4*(lane>>5)
#pragma unroll
  for (int i = 0; i < 2; i++) {
#pragma unroll
    for (int j = 0; j < 2; j++) {
      int gc = col0 + wn * 64 + j * 32 + l31;
      float bv = bias ? bias[gc] : 0.0f;
#pragma unroll
      for (int r = 0; r < 16; r++) {
        int gr = row0 + wm * 64 + i * 32 + (r & 3) + 8 * (r >> 2) + 4 * lh;
        C[(size_t)gr * N + gc] = f2b(acc[i][j][r] + bv);
      }
    }
  }
}

// ---------------- windowed attention, V-free (G-gather) ----------------------
// TWO CONSECUTIVE WINDOWS PER WAVE (R5-proven score structure, K stride 1024).
// After softmax: probs[c] = sum_{h,t} attn[h,t]*G[pos,c*8+h] (+bc incl. folded
// v-bias). PV loop, V loads, and Wc head-dot are eliminated.
__global__ __launch_bounds__(256)
void attn_kernel(const unsigned short* __restrict__ q,
                 const unsigned short* __restrict__ kb,
                 const float* __restrict__ G, const float* __restrict__ bc,
                 float* __restrict__ out) {
  const int g = blockIdx.x;                     // 0..1635
  const int xcd = g & 7, idx = g >> 3;
  const int logical = (xcd < 4) ? (xcd * 205 + idx)
                                : (820 + (xcd - 4) * 204 + idx);
  const int wave = threadIdx.x >> 6, lane = threadIdx.x & 63;
  const int p = logical * 4 + wave;             // pair id 0..6543
  const int m0 = 2 * p, m1 = m0 + 1;
  const int b0 = m0 / NW_, n0 = m0 - b0 * NW_;
  const int b1 = m1 / NW_, n1 = m1 - b1 * NW_;
  const bool adj = (n0 != NW_ - 1);             // same b, n1 = n0+1
  const size_t rb0 = (size_t)b0 * L_ * 1024;
  const size_t rb1 = (size_t)b1 * L_ * 1024;
  const int d0 = lane * 16;

  const unsigned short* qp0 = q + (size_t)m0 * D_ + d0;
  uint4 qa0 = *(const uint4*)qp0, qa1 = *(const uint4*)(qp0 + 8);
  const unsigned short* qp1 = q + (size_t)m1 * D_ + d0;
  uint4 qb0 = *(const uint4*)qp1, qb1 = *(const uint4*)(qp1 + 8);

  // ---- scores over 16 shared positions ----
  float svA[T_], svB[T_];
#pragma unroll
  for (int t = 0; t < T_ + W_; t++) {
    uint4 k0, k1;
    bool liveA = false;
    if (t < T_) {                               // window A position
      int posA = W_ * n0 + t;
      float sc = 0.f;
      if (posA < L_) {
        const unsigned short* kr = kb + rb0 + (size_t)posA * 1024 + d0;
        k0 = *(const uint4*)kr; k1 = *(const uint4*)(kr + 8);
        liveA = true;
        sc = dot8(qa0, k0) + dot8(qa1, k1);
      }
      sc += __shfl_xor(sc, 1);
      sc += __shfl_xor(sc, 2);
      sc += __shfl_xor(sc, 4);
      svA[t] = sc * 0.08838834764831845f;       // 1/sqrt(128)
    }
    if (t >= W_) {                              // window B position
      int tb = t - W_;
      int posB = W_ * n1 + tb;
      float sc = 0.f;
      if (posB < L_) {
        uint4 j0, j1;
        if (adj && liveA) { j0 = k0; j1 = k1; } // same row as A's load
        else {
          const unsigned short* kr = kb + rb1 + (size_t)posB * 1024 + d0;
          j0 = *(const uint4*)kr; j1 = *(const uint4*)(kr + 8);
        }
        sc = dot8(qb0, j0) + dot8(qb1, j1);
      }
      sc += __shfl_xor(sc, 1);
      sc += __shfl_xor(sc, 2);
      sc += __shfl_xor(sc, 4);
      svB[tb] = sc * 0.08838834764831845f;
    }
  }

  // ---- softmax per window ----
  {
    float mx = svA[0];
#pragma unroll
    for (int t = 1; t < T_; t++) mx = fmaxf(mx, svA[t]);
    float sum = 0.f;
#pragma unroll
    for (int t = 0; t < T_; t++) { svA[t] = expf(svA[t] - mx); sum += svA[t]; }
    float inv = 1.f / sum;
#pragma unroll
    for (int t = 0; t < T_; t++) svA[t] *= inv;
  }
  {
    float mx = svB[0];
#pragma unroll
    for (int t = 1; t < T_; t++) mx = fmaxf(mx, svB[t]);
    float sum = 0.f;
#pragma unroll
    for (int t = 0; t < T_; t++) { svB[t] = expf(svB[t] - mx); sum += svB[t]; }
    float inv = 1.f / sum;
#pragma unroll
    for (int t = 0; t < T_; t++) svB[t] *= inv;
  }

  // ---- G gather: lane (s=l&7, h=l>>3) handles t in {s, s+8} for its head ----
  float pA0 = 0.f, pA1 = 0.f, pB0 = 0.f, pB1 = 0.f;
  {
    const int s = lane & 7, hh = lane >> 3;
#pragma unroll
    for (int rep = 0; rep < 2; rep++) {
      int t = s + 8 * rep;
      if (t < T_) {
        int posA = W_ * n0 + t;
        if (posA < L_) {
          const float* ga = G + ((size_t)b0 * L_ + posA) * 16 + hh;
          pA0 += svA[t] * ga[0];
          pA1 += svA[t] * ga[8];
        }
        int posB = W_ * n1 + t;
        if (posB < L_) {
          const float* gb = G + ((size_t)b1 * L_ + posB) * 16 + hh;
          pB0 += svB[t] * gb[0];
          pB1 += svB[t] * gb[8];
        }
      }
    }
  }
#pragma unroll
  for (int off = 32; off > 0; off >>= 1) {
    pA0 += __shfl_down(pA0, off);
    pA1 += __shfl_down(pA1, off);
    pB0 += __shfl_down(pB0, off);
    pB1 += __shfl_down(pB1, off);
  }

  if (lane == 0) {
    {
      float s0 = pA0 + bc[0], s1 = pA1 + bc[1];
      float smx = fmaxf(s0, s1);
      float lse = smx + logf(expf(s0 - smx) + expf(s1 - smx));
      size_t row = (size_t)b0 * L_ + (size_t)(W_ * n0);
      out[row * 2 + 0] = s0 - lse;
      out[row * 2 + 1] = s1 - lse;
    }
    {
      float s0 = pB0 + bc[0], s1 = pB1 + bc[1];
      float smx = fmaxf(s0, s1);
      float lse = smx + logf(expf(s0 - smx) + expf(s1 - smx));
      size_t row = (size_t)b1 * L_ + (size_t)(W_ * n1);
      out[row * 2 + 0] = s0 - lse;
      out[row * 2 + 1] = s1 - lse;
    }
  }
}

extern "C" void kernel_launch(void* const* d_in, const int* in_sizes, int n_in,
                              void* d_out, int out_size, void* d_ws, size_t ws_size,
                              hipStream_t stream) {
  const float* x          = (const float*)d_in[0];
  const float* in_proj_w  = (const float*)d_in[1];
  const float* in_proj_b  = (const float*)d_in[2];
  const float* out_proj_w = (const float*)d_in[3];
  const float* out_proj_b = (const float*)d_in[4];
  const float* out_w      = (const float*)d_in[5];
  const float* out_b      = (const float*)d_in[6];
  float* out = (float*)d_out;

  // workspace (~322 MB):
  //   [0, 32MB)     qout (MQP x 1024 bf16)
  //   [32MB)        in_proj_w bf16 (wq|wk|wv)  (6 MB)
  //   [40MB)        Wc (2x1024 f32), bc, Wcp (16x2048 f32), WvHb (16x1024 bf16)
  //   [48MB)        xb = x bf16, (B*L) x 1024   (128 MB)
  //   [176MB)       kb = K bf16, (B*L) x 1024   (128 MB)
  //   [304MB)       G  = fp32 (B*L) x 16        (4 MB)
  char* ws = (char*)d_ws;
  unsigned short* qout = (unsigned short*)(ws);
  unsigned short* win  = (unsigned short*)(ws + 33554432);
  float*          Wc   = (float*)(ws + 41943040);
  float*          bc   = (float*)(ws + 41951232);
  float*          Wcp  = (float*)(ws + 41959424);
  unsigned short* WvHb = (unsigned short*)(ws + 42090496);
  unsigned short* xb   = (unsigned short*)(ws + 50331648);
  unsigned short* kb   = (unsigned short*)(ws + 184549376);
  float*          G    = (float*)(ws + 318767104);

  // mega1: cvt_x [0,2048) | cvt_w [2048,2304) | fill [2304,2816) | wc_part [2816,2944)
  mega1_kernel<<<2944, 256, 0, stream>>>(x, xb, in_proj_w, win,
                                         out_w, out_proj_w, Wcp, out);
  wc_reduce_kernel<<<8, 256, 0, stream>>>(Wcp, out_w, out_proj_b, out_b, Wc, bc);
  wvh_kernel<<<16, 256, 0, stream>>>(Wcp, in_proj_w, in_proj_b, bc, WvHb);

  dim3 gk(8, 512);    // K-only GEMM: N=1024, M=65536 (V eliminated)
  gemm_bt_kernel<false><<<gk, 256, 0, stream>>>(xb, win + 1048576, kb,
                                                in_proj_b + 1024, 1024, 1024);
  dim3 gq(8, 103);    // M=13184, N=1024; A = bf16 xb with fused center-gather
  gemm_bt_kernel<true><<<gq, 256, 0, stream>>>(xb, win, qout, in_proj_b, 1024, 1024);

  gk_kernel<<<1024, 256, 0, stream>>>(xb, WvHb, G);   // G = xb @ WvHb^T (fp32)

  attn_kernel<<<1636, 256, 0, stream>>>(qout, kb, G, bc, out);
}

// Round 8
// 680.566 us; speedup vs baseline: 1.2711x; 1.0538x over previous
//
#include <hip/hip_runtime.h>

#define B_  32
#define L_  2048
#define D_  1024
#define NW_ 409
#define W_  5
#define T_  11
#define H_  8
#define HD_ 128
#define MQ  (B_*NW_)   // 13088
#define MQP 13184      // 103*128 (padded M for q GEMM)

typedef __attribute__((ext_vector_type(16))) float f32x16;
typedef __attribute__((ext_vector_type(4)))  float f32x4;
typedef __attribute__((ext_vector_type(8))) __bf16 bf16x8;

__device__ __forceinline__ float b2f(unsigned short u) {
  union { unsigned int i; float f; } x; x.i = ((unsigned int)u) << 16; return x.f;
}
__device__ __forceinline__ unsigned short f2b(float f) {
  union { float f; unsigned int i; } x; x.f = f;
  unsigned int r = (x.i + 0x7FFFu + ((x.i >> 16) & 1u)) >> 16;
  return (unsigned short)r;
}
__device__ __forceinline__ float2 bf2x(unsigned int u) {
  union { unsigned int i; float f; } lo, hi;
  lo.i = u << 16; hi.i = u & 0xffff0000u;
  return make_float2(lo.f, hi.f);
}

__device__ __forceinline__ void async_copy16(const void* g, void* l) {
  __builtin_amdgcn_global_load_lds(
      (const __attribute__((address_space(1))) void*)g,
      (__attribute__((address_space(3))) void*)l, 16, 0, 0);
}

// dot of 8 bf16 pairs packed in uint4
__device__ __forceinline__ float dot8(uint4 a, uint4 b) {
  float2 x, y; float s = 0.f;
  x = bf2x(a.x); y = bf2x(b.x); s += x.x * y.x + x.y * y.y;
  x = bf2x(a.y); y = bf2x(b.y); s += x.x * y.x + x.y * y.y;
  x = bf2x(a.z); y = bf2x(b.z); s += x.x * y.x + x.y * y.y;
  x = bf2x(a.w); y = bf2x(b.w); s += x.x * y.x + x.y * y.y;
  return s;
}

// ================= mega1: {cvt_x | cvt_w | fill | wc_part} by block range ====
__device__ __forceinline__ void cvt_body(const float* __restrict__ in,
                                         unsigned short* __restrict__ out,
                                         int i0, int stride, int n4) {
  for (int i = i0; i < n4; i += stride) {
    float4 v = ((const float4*)in)[i];
    ushort4 o;
    o.x = f2b(v.x); o.y = f2b(v.y); o.z = f2b(v.z); o.w = f2b(v.w);
    ((ushort4*)out)[i] = o;
  }
}
__global__ __launch_bounds__(256)
void mega1_kernel(const float* __restrict__ x, unsigned short* __restrict__ xb,
                  const float* __restrict__ ipw, unsigned short* __restrict__ win,
                  const float* __restrict__ ow, const float* __restrict__ opw,
                  float* __restrict__ Wcp, float* __restrict__ out) {
  const int blk = blockIdx.x, tid = threadIdx.x;
  if (blk < 2048) {                       // cvt_x: 256 MB fp32 -> 128 MB bf16
    cvt_body(x, xb, blk * 256 + tid, 2048 * 256, 16777216);
  } else if (blk < 2304) {                // cvt_w: in_proj_w -> bf16
    cvt_body(ipw, win, (blk - 2048) * 256 + tid, 256 * 256, 786432);
  } else if (blk < 2816) {                // fill out with log(0.5)
    out[(blk - 2304) * 256 + tid] = -0.69314718055994531f;
  } else {                                // wc_part: 128 blocks
    int bb = blk - 2816;
    int eb = bb >> 3, seg = bb & 7;
    int d = seg * 256 + tid;              // 0..2047
    int c = d >> 10, dd = d & 1023;
    float acc = 0.f;
    int e0 = eb * 64;
#pragma unroll 8
    for (int e = e0; e < e0 + 64; e++) acc += ow[c * D_ + e] * opw[e * D_ + dd];
    Wcp[eb * 2048 + d] = acc;
  }
}

__global__ void wc_reduce_kernel(const float* __restrict__ Wcp,
                                 const float* __restrict__ ow, const float* __restrict__ opb,
                                 const float* __restrict__ ob,
                                 float* __restrict__ Wc, float* __restrict__ bc) {
  int d = blockIdx.x * 256 + threadIdx.x;
  float s = 0.f;
#pragma unroll
  for (int eb = 0; eb < 16; eb++) s += Wcp[eb * 2048 + d];
  Wc[d] = s;
  if (blockIdx.x == 0 && threadIdx.x < 128) {
    int c = threadIdx.x >> 6, lane = threadIdx.x & 63;
    float p = 0.f;
#pragma unroll
    for (int j = 0; j < 16; j++) p += ow[c * D_ + lane + 64 * j] * opb[lane + 64 * j];
#pragma unroll
    for (int off = 32; off > 0; off >>= 1) p += __shfl_down(p, off);
    if (lane == 0) bc[c] = p + ob[c];
  }
}

// ================ WvH: fold Wc into the V projection (V-elimination) =========
// WvH[c,h,e] = sum_{d in head h} Wc[c,d] * wv[d,e]  (2x8x1024, bf16 out).
// 64 blocks = (c,h,jseg): 4x wider than R7's 16-block version (it serialized
// the pre-GEMM chain on 16 CUs). v-bias folds into bc (softmax sums to 1).
__global__ __launch_bounds__(256)
void wvh_kernel(const float* __restrict__ Wcp, const float* __restrict__ ipw,
                const float* __restrict__ ipb, float* __restrict__ bc,
                unsigned short* __restrict__ WvHb) {
  const int c = blockIdx.x >> 5, h = (blockIdx.x >> 2) & 7, j = blockIdx.x & 3;
  const int tid = threadIdx.x;
  __shared__ float wcs[128];
  if (tid < 128) {
    float s = 0.f;
#pragma unroll
    for (int eb = 0; eb < 16; eb++) s += Wcp[eb * 2048 + c * 1024 + h * 128 + tid];
    wcs[tid] = s;
  }
  __syncthreads();
  const float* wv = ipw + 2048 * 1024;
  {
    int e = j * 256 + tid;
    float acc = 0.f;
    for (int dd = 0; dd < 128; dd++)
      acc += wcs[dd] * wv[(size_t)(h * 128 + dd) * 1024 + e];
    WvHb[(c * 8 + h) * 1024 + e] = f2b(acc);
  }
  if (j == 0 && tid == 0) {
    float gb = 0.f;
    for (int dd = 0; dd < 128; dd++) gb += wcs[dd] * ipb[2048 + h * 128 + dd];
    atomicAdd(&bc[c], gb);
  }
}

// ---------------- NT GEMM body, bf16 A, BK=64, 32x32x16 MFMA (R2 layout) -----
// Proven code, unchanged math; now a device body so K-GEMM, q-GEMM and gk
// share one dispatch (tail-packing). Rotated-LDS conflicts (~1.7e7) are hidden
// behind the 2-phase stage+barrier path (T2 regime-gate, m252); R3's
// conflict-free chunk-major layout broke global coalescing and was 1.7x
// SLOWER. Do not "fix" conflicts without an 8-phase schedule.
template<bool GATHER>
__device__ void gemm_body(const unsigned short* __restrict__ A,
                          const unsigned short* __restrict__ Bw,
                          unsigned short* __restrict__ C,
                          const float* __restrict__ bias,
                          int N, int K, int h, int gx, int chunk,
                          unsigned short* sA, unsigned short* sB) {
  const int lg = (h & 7) * chunk + (h >> 3);
  const int bx = lg % gx, by = lg / gx;
  const int tid = threadIdx.x;
  const int row0 = by * 128;
  const int col0 = bx * 128;
  const int wave = tid >> 6, lane = tid & 63;
  const int wm = wave & 1, wn = wave >> 1;
  const int l31 = lane & 31, lh = lane >> 5;

  const unsigned short* Asrc[4];
  const unsigned short* Bsrc[4];
#pragma unroll
  for (int u = 0; u < 4; u++) {
    int c = tid + 256 * u;
    int r = c >> 3, kc = ((c & 7) - r) & 7;
    Bsrc[u] = Bw + (size_t)(col0 + r) * K + kc * 8;
    size_t arow;
    if constexpr (GATHER) {
      int mm = row0 + r;
      if (mm >= MQ) mm = 0;                 // pad rows: any valid src
      int b = mm / NW_, n = mm - b * NW_;
      arow = (size_t)b * L_ + (size_t)(W_ * n + W_);
    } else {
      arow = (size_t)(row0 + r);
    }
    Asrc[u] = A + arow * K + kc * 8;
  }

  int offA[4][2], offB[4][2];
#pragma unroll
  for (int kc = 0; kc < 4; kc++) {
    int c8 = kc * 2 + lh;
#pragma unroll
    for (int i = 0; i < 2; i++) {
      int rb = wn * 64 + i * 32 + l31;
      offB[kc][i] = (rb * 8 + ((c8 + rb) & 7)) * 8;
      int ra = wm * 64 + i * 32 + l31;
      offA[kc][i] = (ra * 8 + ((c8 + ra) & 7)) * 8;
    }
  }

  f32x16 acc[2][2];
#pragma unroll
  for (int i = 0; i < 2; i++)
#pragma unroll
    for (int j = 0; j < 2; j++) acc[i][j] = (f32x16)0.0f;

  for (int kt = 0; kt < K; kt += 64) {
#pragma unroll
    for (int u = 0; u < 4; u++)
      async_copy16(Asrc[u] + kt, &sA[(tid + 256 * u) * 8]);
#pragma unroll
    for (int u = 0; u < 4; u++)
      async_copy16(Bsrc[u] + kt, &sB[(tid + 256 * u) * 8]);
    __syncthreads();
#pragma unroll
    for (int kc = 0; kc < 4; kc++) {
      bf16x8 a0 = *(const bf16x8*)&sA[offA[kc][0]];
      bf16x8 a1 = *(const bf16x8*)&sA[offA[kc][1]];
      bf16x8 b0 = *(const bf16x8*)&sB[offB[kc][0]];
      bf16x8 b1 = *(const bf16x8*)&sB[offB[kc][1]];
      acc[0][0] = __builtin_amdgcn_mfma_f32_32x32x16_bf16(a0, b0, acc[0][0], 0, 0, 0);
      acc[0][1] = __builtin_amdgcn_mfma_f32_32x32x16_bf16(a0, b1, acc[0][1], 0, 0, 0);
      acc[1][0] = __builtin_amdgcn_mfma_f32_32x32x16_bf16(a1, b0, acc[1][0], 0, 0, 0);
      acc[1][1] = __builtin_amdgcn_mfma_f32_32x32x16_bf16(a1, b1, acc[1][1], 0, 0, 0);
    }
    __syncthreads();
  }

  // C/D frag (m74/m101): col=lane&31, row=(reg&3)+8*(reg>>2)+4*(lane>>5)
#pragma unroll
  for (int i = 0; i < 2; i++) {
#pragma unroll
    for (int j = 0; j < 2; j++) {
      int gc = col0 + wn * 64 + j * 32 + l31;
      float bv = bias[gc];
#pragma unroll
      for (int r = 0; r < 16; r++) {
        int gr = row0 + wm * 64 + i * 32 + (r & 3) + 8 * (r >> 2) + 4 * lh;
        C[(size_t)gr * N + gc] = f2b(acc[i][j][r] + bv);
      }
    }
  }
}

// ================ gk body: G = xb @ WvHb^T (65536 x 16), fp32 out ============
// One wave per 16 rows; 16x16x32 MFMA. C/D: col=lane&15, row=(lane>>4)*4+reg.
__device__ void gk_body(const unsigned short* __restrict__ xb,
                        const unsigned short* __restrict__ WvHb,
                        float* __restrict__ G, int blk) {
  const int wave = threadIdx.x >> 6, lane = threadIdx.x & 63;
  const int r0 = (blk * 4 + wave) * 16;
  const int l15 = lane & 15, kh = lane >> 4;
  const unsigned short* ap = xb + (size_t)(r0 + l15) * 1024 + kh * 8;
  const unsigned short* bp = WvHb + l15 * 1024 + kh * 8;
  f32x4 acc = (f32x4)0.0f;
  for (int kt = 0; kt < 1024; kt += 32) {
    bf16x8 a = *(const bf16x8*)(ap + kt);
    bf16x8 b = *(const bf16x8*)(bp + kt);
    acc = __builtin_amdgcn_mfma_f32_16x16x32_bf16(a, b, acc, 0, 0, 0);
  }
#pragma unroll
  for (int r = 0; r < 4; r++)
    G[(size_t)(r0 + kh * 4 + r) * 16 + l15] = acc[r];
}

// ================ fused main: K-GEMM | q-GEMM | gk in one dispatch ===========
// Blocks [0,4096): K = xb@wk^T (grid 8x512, XCD swizzle chunk=512).
// Blocks [4096,4920): q = gather(xb)@wq^T (grid 8x103, chunk=103; 824%8==0).
// Blocks [4920,5944): gk. All three depend only on {xb, win, WvHb}; packing
// lets q/gk blocks backfill the K-GEMM's drain tail (~2.4 blocks/CU).
// Branch is uniform per block -> barriers inside gemm_body are safe.
__global__ __launch_bounds__(256)
void fused_main_kernel(const unsigned short* __restrict__ xb,
                       const unsigned short* __restrict__ win,
                       const unsigned short* __restrict__ WvHb,
                       unsigned short* __restrict__ kb,
                       unsigned short* __restrict__ qout,
                       float* __restrict__ G,
                       const float* __restrict__ ipb) {
  __shared__ __align__(16) unsigned short sA[128 * 64];
  __shared__ __align__(16) unsigned short sB[128 * 64];
  const int b = blockIdx.x;
  if (b < 4096) {
    gemm_body<false>(xb, win + 1048576, kb, ipb + 1024, 1024, 1024,
                     b, 8, 512, sA, sB);
  } else if (b < 4920) {
    gemm_body<true>(xb, win, qout, ipb, 1024, 1024,
                    b - 4096, 8, 103, sA, sB);
  } else {
    gk_body(xb, WvHb, G, b - 4920);
  }
}

// ---------------- windowed attention, V-free (G-gather) ----------------------
// TWO CONSECUTIVE WINDOWS PER WAVE (R5-proven). probs[c] = sum attn*G + bc.
__global__ __launch_bounds__(256)
void attn_kernel(const unsigned short* __restrict__ q,
                 const unsigned short* __restrict__ kb,
                 const float* __restrict__ G, const float* __restrict__ bc,
                 float* __restrict__ out) {
  const int g = blockIdx.x;                     // 0..1635
  const int xcd = g & 7, idx = g >> 3;
  const int logical = (xcd < 4) ? (xcd * 205 + idx)
                                : (820 + (xcd - 4) * 204 + idx);
  const int wave = threadIdx.x >> 6, lane = threadIdx.x & 63;
  const int p = logical * 4 + wave;             // pair id 0..6543
  const int m0 = 2 * p, m1 = m0 + 1;
  const int b0 = m0 / NW_, n0 = m0 - b0 * NW_;
  const int b1 = m1 / NW_, n1 = m1 - b1 * NW_;
  const bool adj = (n0 != NW_ - 1);             // same b, n1 = n0+1
  const size_t rb0 = (size_t)b0 * L_ * 1024;
  const size_t rb1 = (size_t)b1 * L_ * 1024;
  const int d0 = lane * 16;

  const unsigned short* qp0 = q + (size_t)m0 * D_ + d0;
  uint4 qa0 = *(const uint4*)qp0, qa1 = *(const uint4*)(qp0 + 8);
  const unsigned short* qp1 = q + (size_t)m1 * D_ + d0;
  uint4 qb0 = *(const uint4*)qp1, qb1 = *(const uint4*)(qp1 + 8);

  // ---- scores over 16 shared positions ----
  float svA[T_], svB[T_];
#pragma unroll
  for (int t = 0; t < T_ + W_; t++) {
    uint4 k0, k1;
    bool liveA = false;
    if (t < T_) {                               // window A position
      int posA = W_ * n0 + t;
      float sc = 0.f;
      if (posA < L_) {
        const unsigned short* kr = kb + rb0 + (size_t)posA * 1024 + d0;
        k0 = *(const uint4*)kr; k1 = *(const uint4*)(kr + 8);
        liveA = true;
        sc = dot8(qa0, k0) + dot8(qa1, k1);
      }
      sc += __shfl_xor(sc, 1);
      sc += __shfl_xor(sc, 2);
      sc += __shfl_xor(sc, 4);
      svA[t] = sc * 0.08838834764831845f;       // 1/sqrt(128)
    }
    if (t >= W_) {                              // window B position
      int tb = t - W_;
      int posB = W_ * n1 + tb;
      float sc = 0.f;
      if (posB < L_) {
        uint4 j0, j1;
        if (adj && liveA) { j0 = k0; j1 = k1; } // same row as A's load
        else {
          const unsigned short* kr = kb + rb1 + (size_t)posB * 1024 + d0;
          j0 = *(const uint4*)kr; j1 = *(const uint4*)(kr + 8);
        }
        sc = dot8(qb0, j0) + dot8(qb1, j1);
      }
      sc += __shfl_xor(sc, 1);
      sc += __shfl_xor(sc, 2);
      sc += __shfl_xor(sc, 4);
      svB[tb] = sc * 0.08838834764831845f;
    }
  }

  // ---- softmax per window ----
  {
    float mx = svA[0];
#pragma unroll
    for (int t = 1; t < T_; t++) mx = fmaxf(mx, svA[t]);
    float sum = 0.f;
#pragma unroll
    for (int t = 0; t < T_; t++) { svA[t] = expf(svA[t] - mx); sum += svA[t]; }
    float inv = 1.f / sum;
#pragma unroll
    for (int t = 0; t < T_; t++) svA[t] *= inv;
  }
  {
    float mx = svB[0];
#pragma unroll
    for (int t = 1; t < T_; t++) mx = fmaxf(mx, svB[t]);
    float sum = 0.f;
#pragma unroll
    for (int t = 0; t < T_; t++) { svB[t] = expf(svB[t] - mx); sum += svB[t]; }
    float inv = 1.f / sum;
#pragma unroll
    for (int t = 0; t < T_; t++) svB[t] *= inv;
  }

  // ---- G gather: lane (s=l&7, h=l>>3) handles t in {s, s+8} for its head ----
  float pA0 = 0.f, pA1 = 0.f, pB0 = 0.f, pB1 = 0.f;
  {
    const int s = lane & 7, hh = lane >> 3;
#pragma unroll
    for (int rep = 0; rep < 2; rep++) {
      int t = s + 8 * rep;
      if (t < T_) {
        int posA = W_ * n0 + t;
        if (posA < L_) {
          const float* ga = G + ((size_t)b0 * L_ + posA) * 16 + hh;
          pA0 += svA[t] * ga[0];
          pA1 += svA[t] * ga[8];
        }
        int posB = W_ * n1 + t;
        if (posB < L_) {
          const float* gb = G + ((size_t)b1 * L_ + posB) * 16 + hh;
          pB0 += svB[t] * gb[0];
          pB1 += svB[t] * gb[8];
        }
      }
    }
  }
#pragma unroll
  for (int off = 32; off > 0; off >>= 1) {
    pA0 += __shfl_down(pA0, off);
    pA1 += __shfl_down(pA1, off);
    pB0 += __shfl_down(pB0, off);
    pB1 += __shfl_down(pB1, off);
  }

  if (lane == 0) {
    {
      float s0 = pA0 + bc[0], s1 = pA1 + bc[1];
      float smx = fmaxf(s0, s1);
      float lse = smx + logf(expf(s0 - smx) + expf(s1 - smx));
      size_t row = (size_t)b0 * L_ + (size_t)(W_ * n0);
      out[row * 2 + 0] = s0 - lse;
      out[row * 2 + 1] = s1 - lse;
    }
    {
      float s0 = pB0 + bc[0], s1 = pB1 + bc[1];
      float smx = fmaxf(s0, s1);
      float lse = smx + logf(expf(s0 - smx) + expf(s1 - smx));
      size_t row = (size_t)b1 * L_ + (size_t)(W_ * n1);
      out[row * 2 + 0] = s0 - lse;
      out[row * 2 + 1] = s1 - lse;
    }
  }
}

extern "C" void kernel_launch(void* const* d_in, const int* in_sizes, int n_in,
                              void* d_out, int out_size, void* d_ws, size_t ws_size,
                              hipStream_t stream) {
  const float* x          = (const float*)d_in[0];
  const float* in_proj_w  = (const float*)d_in[1];
  const float* in_proj_b  = (const float*)d_in[2];
  const float* out_proj_w = (const float*)d_in[3];
  const float* out_proj_b = (const float*)d_in[4];
  const float* out_w      = (const float*)d_in[5];
  const float* out_b      = (const float*)d_in[6];
  float* out = (float*)d_out;

  // workspace (~322 MB):
  //   [0, 32MB)     qout (MQP x 1024 bf16)
  //   [32MB)        in_proj_w bf16 (wq|wk|wv)  (6 MB)
  //   [40MB)        Wc (2x1024 f32), bc, Wcp (16x2048 f32), WvHb (16x1024 bf16)
  //   [48MB)        xb = x bf16, (B*L) x 1024   (128 MB)
  //   [176MB)       kb = K bf16, (B*L) x 1024   (128 MB)
  //   [304MB)       G  = fp32 (B*L) x 16        (4 MB)
  char* ws = (char*)d_ws;
  unsigned short* qout = (unsigned short*)(ws);
  unsigned short* win  = (unsigned short*)(ws + 33554432);
  float*          Wc   = (float*)(ws + 41943040);
  float*          bc   = (float*)(ws + 41951232);
  float*          Wcp  = (float*)(ws + 41959424);
  unsigned short* WvHb = (unsigned short*)(ws + 42090496);
  unsigned short* xb   = (unsigned short*)(ws + 50331648);
  unsigned short* kb   = (unsigned short*)(ws + 184549376);
  float*          G    = (float*)(ws + 318767104);

  // mega1: cvt_x [0,2048) | cvt_w [2048,2304) | fill [2304,2816) | wc_part [2816,2944)
  mega1_kernel<<<2944, 256, 0, stream>>>(x, xb, in_proj_w, win,
                                         out_w, out_proj_w, Wcp, out);
  wc_reduce_kernel<<<8, 256, 0, stream>>>(Wcp, out_w, out_proj_b, out_b, Wc, bc);
  wvh_kernel<<<64, 256, 0, stream>>>(Wcp, in_proj_w, in_proj_b, bc, WvHb);

  // K-GEMM + q-GEMM + gk in one tail-packed dispatch
  fused_main_kernel<<<5944, 256, 0, stream>>>(xb, win, WvHb, kb, qout, G,
                                              in_proj_b);

  attn_kernel<<<1636, 256, 0, stream>>>(qout, kb, G, bc, out);
}